// Round 12
// baseline (416.061 us; speedup 1.0000x reference)
//
#include <hip/hip_runtime.h>
#include <math.h>

// Problem constants
#define N_NODES 50000
#define N_EDGES 800000
#define IN_CH 128
#define HID 256
#define OUT_CH 40
#define GRP 6250          // nodes per dst-group (8 groups)
#define HGRP 3125         // half-group window: 16 windows x 32 chunks = 512 blocks
#define NCHUNK 32         // edge-chunks

typedef unsigned short u16;
typedef unsigned char u8;
typedef __attribute__((ext_vector_type(8))) short bf16x8;
typedef __attribute__((ext_vector_type(8))) unsigned short u16x8;
typedef __attribute__((ext_vector_type(4))) float f32x4;
typedef __attribute__((ext_vector_type(2))) float f32x2;

__device__ __forceinline__ float bf2f(u16 u) {
    union { unsigned int i; float f; } v; v.i = ((unsigned int)u) << 16; return v.f;
}
__device__ __forceinline__ u16 f2bf(float f) {   // round-to-nearest-even
    union { float f; unsigned int i; } v; v.f = f;
    unsigned int x = v.i;
    x += 0x7fffu + ((x >> 16) & 1u);
    return (u16)(x >> 16);
}

#define GLOBAL_AS __attribute__((address_space(1)))
#define LDS_AS __attribute__((address_space(3)))
__device__ __forceinline__ void async_cp16(const void* g, void* l) {
    __builtin_amdgcn_global_load_lds((const GLOBAL_AS unsigned int*)g,
                                     (LDS_AS unsigned int*)l, 16, 0, 0);
}

// ===========================================================================
// Fused prep v11: x->{bf16,fp8} + weight packing + u16 edge copies + the
// degree histogram (reads dst straight from the int32 edge_index).
// Block ranges: [0,6250) conv_x; [6250,7813) edge-compress; [7813,7880)
// weight-pack; [7880,8392) histogram (16 half-group windows x 32 chunks).
// ===========================================================================
__device__ __forceinline__ void pack_w(
    const float* __restrict__ in, u16* __restrict__ out, int K, int N, int c)
{
    for (int k = threadIdx.x; k < K; k += 256) {
        int kk32 = k >> 5, quad = (k >> 3) & 3, e = k & 7;
        size_t base = (((size_t)c * (K >> 5) + kk32) * 64 + quad * 16) * 8 + e;
#pragma unroll
        for (int li = 0; li < 16; li++) {
            int n = c * 16 + li;
            float v = (n < N) ? in[(size_t)k * N + n] : 0.f;
            out[base + (size_t)li * 8] = f2bf(v);
        }
    }
}

__global__ __launch_bounds__(256) void prep_fused(
    const float* __restrict__ x, u16* __restrict__ xb, u8* __restrict__ xf8,
    const int* __restrict__ ei, u16* __restrict__ e16,
    const float* __restrict__ W1a, const float* __restrict__ W2a,
    const float* __restrict__ W1b, const float* __restrict__ W2b,
    const float* __restrict__ Wlin,
    u16* __restrict__ W1aPk, u16* __restrict__ W2aPk,
    u16* __restrict__ W1bPk, u16* __restrict__ W2bPk, u16* __restrict__ WlinPk,
    u16* __restrict__ partial)
{
    __shared__ int hist[HGRP];     // 12.5 KB (used only by histogram blocks)
    int b = blockIdx.x;
    if (b < 6250) {
        int i = b * 256 + threadIdx.x;
        float4 v = ((const float4*)x)[i];
        ushort4 o;
        o.x = f2bf(v.x); o.y = f2bf(v.y); o.z = f2bf(v.z); o.w = f2bf(v.w);
        ((ushort4*)xb)[i] = o;
        int p = __builtin_amdgcn_cvt_pk_fp8_f32(v.x, v.y, 0, false);
        p = __builtin_amdgcn_cvt_pk_fp8_f32(v.z, v.w, p, true);
        ((unsigned int*)xf8)[i] = (unsigned int)p;
    } else if (b < 7813) {
        int i = (b - 6250) * 256 + threadIdx.x;
        if (i < (2 * N_EDGES) / 4) {
            int4 v = ((const int4*)ei)[i];
            ushort4 o;
            o.x = (u16)v.x; o.y = (u16)v.y; o.z = (u16)v.z; o.w = (u16)v.w;
            ((ushort4*)e16)[i] = o;
        }
    } else if (b < 7880) {
        int t = b - 7813;
        if (t < 16)       pack_w(W1a, W1aPk, IN_CH, HID, t);
        else if (t < 32)  pack_w(W2a, W2aPk, HID, HID, t - 16);
        else if (t < 48)  pack_w(W1b, W1bPk, HID, HID, t - 32);
        else if (t < 64)  pack_w(W2b, W2bPk, HID, HID, t - 48);
        else              pack_w(Wlin, WlinPk, 2 * HID, OUT_CH, t - 64);
    } else {
        // ---- degree histogram, straight from int32 dst ----
        const int hb = b - 7880;           // [0,512)
        const int gh = hb & 15;
        const int sub = hb >> 4;
        const int lo = gh * HGRP;
        const int CH = N_EDGES / NCHUNK;   // 25000
        for (int i = threadIdx.x; i < HGRP; i += 256) hist[i] = 0;
        __syncthreads();
        const int4* dsts = (const int4*)(ei + N_EDGES + sub * CH);
        for (int k = threadIdx.x; k < CH / 4; k += 256) {
            int4 d = dsts[k];
            int r0 = d.x - lo, r1 = d.y - lo;
            int r2 = d.z - lo, r3 = d.w - lo;
            if ((unsigned)r0 < (unsigned)HGRP) atomicAdd(&hist[r0], 1);
            if ((unsigned)r1 < (unsigned)HGRP) atomicAdd(&hist[r1], 1);
            if ((unsigned)r2 < (unsigned)HGRP) atomicAdd(&hist[r2], 1);
            if ((unsigned)r3 < (unsigned)HGRP) atomicAdd(&hist[r3], 1);
        }
        __syncthreads();
        u16* po = partial + (size_t)(sub * 8 + (gh >> 1)) * GRP + (gh & 1) * HGRP;
        for (int i = threadIdx.x; i < HGRP; i += 256) po[i] = (u16)hist[i];
    }
}

// ===========================================================================
// scan1 (absorbs deg_cp): 196 blocks, one node per thread.
// ===========================================================================
__global__ __launch_bounds__(256) void scan1(
    const u16* __restrict__ partial, u16* __restrict__ chunkpref,
    int* __restrict__ excl, int* __restrict__ partials_out)
{
    __shared__ int lds[256];
    const int tid = threadIdx.x;
    const int node = blockIdx.x * 256 + tid;
    int d = 0;
    if (node < N_NODES) {
        int g = node / GRP;
        int off = node - g * GRP;
#pragma unroll
        for (int sub = 0; sub < NCHUNK; sub++) {
            chunkpref[(size_t)sub * N_NODES + node] = (u16)d;   // exclusive
            d += partial[(size_t)(sub * 8 + g) * GRP + off];
        }
    }
    lds[tid] = d;
    __syncthreads();
    for (int off = 1; off < 256; off <<= 1) {
        int t = (tid >= off) ? lds[tid - off] : 0;
        __syncthreads();
        lds[tid] += t;
        __syncthreads();
    }
    if (node < N_NODES) excl[node] = lds[tid] - d;
    if (tid == 255) partials_out[blockIdx.x] = lds[255];
}

// ===========================================================================
// scan3: add block prefixes (196 partials, 256-wide scan) + sentinel.
// ===========================================================================
__global__ __launch_bounds__(256) void scan3(
    int* __restrict__ excl, const int* __restrict__ partials,
    int* __restrict__ sentinel, int nPart)
{
    __shared__ int lds[256];
    __shared__ int bp[256];
    const int tid = threadIdx.x;
    int orig = (tid < nPart) ? partials[tid] : 0;
    lds[tid] = orig;
    __syncthreads();
    for (int off = 1; off < 256; off <<= 1) {
        int t = (tid >= off) ? lds[tid - off] : 0;
        __syncthreads();
        lds[tid] += t;
        __syncthreads();
    }
    bp[tid] = lds[tid] - orig;
    __syncthreads();
    const int idx = blockIdx.x * 256 + tid;
    if (idx < N_NODES) excl[idx] += bp[blockIdx.x];
    if (idx == 0) sentinel[0] = N_EDGES;   // rowp[N_NODES] = N_EDGES
}

// ===========================================================================
// csr_fill: atomic-FREE placement, half-group windows (512 blocks, 2/CU).
// ===========================================================================
__global__ __launch_bounds__(256) void csr_fill(
    const u16* __restrict__ src16, const u16* __restrict__ dst16,
    const int* __restrict__ rowp, const u16* __restrict__ chunkpref,
    u16* __restrict__ csr_src)
{
    __shared__ int cur[HGRP];     // 12.5 KB
    const int gh = blockIdx.x & 15;
    const int c = blockIdx.x >> 4;
    const int lo = gh * HGRP;
    const int CH = N_EDGES / NCHUNK;          // 25000
    const u16* cp = chunkpref + (size_t)c * N_NODES + lo;
    for (int i = threadIdx.x; i < HGRP; i += 256)
        cur[i] = rowp[lo + i] + cp[i];
    __syncthreads();
    const ushort4* dsts = (const ushort4*)(dst16 + c * CH);
    const ushort4* srcs = (const ushort4*)(src16 + c * CH);
    for (int k = threadIdx.x; k < CH / 4; k += 256) {
        ushort4 d = dsts[k];
        ushort4 sc = srcs[k];
        int r0 = (int)d.x - lo, r1 = (int)d.y - lo;
        int r2 = (int)d.z - lo, r3 = (int)d.w - lo;
        if ((unsigned)r0 < (unsigned)HGRP) { int p = atomicAdd(&cur[r0], 1); csr_src[p] = sc.x; }
        if ((unsigned)r1 < (unsigned)HGRP) { int p = atomicAdd(&cur[r1], 1); csr_src[p] = sc.y; }
        if ((unsigned)r2 < (unsigned)HGRP) { int p = atomicAdd(&cur[r2], 1); csr_src[p] = sc.z; }
        if ((unsigned)r3 < (unsigned)HGRP) { int p = atomicAdd(&cur[r3], 1); csr_src[p] = sc.w; }
    }
}

// ===========================================================================
// Gather aggregation: wide per-edge gathers (16B/lane dwordx4), unroll x4.
// ===========================================================================

// IN_CH=128: 8 lanes/node (16B/lane), 8 nodes/wave, 32 nodes/block.
__global__ __launch_bounds__(256) void gather_agg_f8_128(
    const u16* __restrict__ feat_bf, const u8* __restrict__ feat_f8,
    const int* __restrict__ row_ptr, const int* __restrict__ row_end,
    const u16* __restrict__ csr_src, u16* __restrict__ out)
{
    const int tid = threadIdx.x;
    const int lane = tid & 63;
    const int wv = tid >> 6;
    const int li = lane & 7;
    int node = blockIdx.x * 32 + wv * 8 + (lane >> 3);
    const bool valid = node < N_NODES;
    if (!valid) node = N_NODES - 1;

    int j = row_ptr[node];
    int deg = valid ? (row_end[node] - j) : 0;

    float acc[16];
    {
        u16x8 s0 = *(const u16x8*)(feat_bf + (size_t)node * IN_CH + li * 16);
        u16x8 s1 = *(const u16x8*)(feat_bf + (size_t)node * IN_CH + li * 16 + 8);
#pragma unroll
        for (int q = 0; q < 8; q++) { acc[q] = bf2f(s0[q]); acc[8 + q] = bf2f(s1[q]); }
    }

    int maxdeg = deg;
#pragma unroll
    for (int off = 8; off < 64; off <<= 1)
        maxdeg = max(maxdeg, __shfl_xor(maxdeg, off, 64));

    for (int it = 0; it < maxdeg; it += 4) {
        int4 g0 = {0,0,0,0}, g1 = {0,0,0,0}, g2 = {0,0,0,0}, g3 = {0,0,0,0};
        if (it < deg)
            g0 = *(const int4*)(feat_f8 + (size_t)csr_src[j + it] * IN_CH + li * 16);
        if (it + 1 < deg)
            g1 = *(const int4*)(feat_f8 + (size_t)csr_src[j + it + 1] * IN_CH + li * 16);
        if (it + 2 < deg)
            g2 = *(const int4*)(feat_f8 + (size_t)csr_src[j + it + 2] * IN_CH + li * 16);
        if (it + 3 < deg)
            g3 = *(const int4*)(feat_f8 + (size_t)csr_src[j + it + 3] * IN_CH + li * 16);
#pragma unroll
        for (int q = 0; q < 4; q++) {
            int w0 = (&g0.x)[q], w1 = (&g1.x)[q], w2 = (&g2.x)[q], w3 = (&g3.x)[q];
            f32x2 l0 = __builtin_amdgcn_cvt_pk_f32_fp8(w0, false);
            f32x2 h0 = __builtin_amdgcn_cvt_pk_f32_fp8(w0, true);
            f32x2 l1 = __builtin_amdgcn_cvt_pk_f32_fp8(w1, false);
            f32x2 h1 = __builtin_amdgcn_cvt_pk_f32_fp8(w1, true);
            f32x2 l2 = __builtin_amdgcn_cvt_pk_f32_fp8(w2, false);
            f32x2 h2 = __builtin_amdgcn_cvt_pk_f32_fp8(w2, true);
            f32x2 l3 = __builtin_amdgcn_cvt_pk_f32_fp8(w3, false);
            f32x2 h3 = __builtin_amdgcn_cvt_pk_f32_fp8(w3, true);
            acc[q * 4 + 0] += (l0.x + l1.x) + (l2.x + l3.x);
            acc[q * 4 + 1] += (l0.y + l1.y) + (l2.y + l3.y);
            acc[q * 4 + 2] += (h0.x + h1.x) + (h2.x + h3.x);
            acc[q * 4 + 3] += (h0.y + h1.y) + (h2.y + h3.y);
        }
    }

    if (valid) {
        u16x8 o0, o1;
#pragma unroll
        for (int q = 0; q < 8; q++) { o0[q] = f2bf(acc[q]); o1[q] = f2bf(acc[8 + q]); }
        *(u16x8*)(out + (size_t)node * IN_CH + li * 16) = o0;
        *(u16x8*)(out + (size_t)node * IN_CH + li * 16 + 8) = o1;
    }
}

// HID=256: 16 lanes/node (16B/lane), 4 nodes/wave, 16 nodes/block (no tail).
__global__ __launch_bounds__(256) void gather_agg_f8_256(
    const u16* __restrict__ feat_bf, const u8* __restrict__ feat_f8,
    const int* __restrict__ row_ptr, const int* __restrict__ row_end,
    const u16* __restrict__ csr_src, u16* __restrict__ out)
{
    const int tid = threadIdx.x;
    const int lane = tid & 63;
    const int wv = tid >> 6;
    const int li = lane & 15;
    const int node = blockIdx.x * 16 + wv * 4 + (lane >> 4);   // 3125*16 = 50000

    int j = row_ptr[node];
    int deg = row_end[node] - j;

    float acc[16];
    {
        u16x8 s0 = *(const u16x8*)(feat_bf + (size_t)node * HID + li * 16);
        u16x8 s1 = *(const u16x8*)(feat_bf + (size_t)node * HID + li * 16 + 8);
#pragma unroll
        for (int q = 0; q < 8; q++) { acc[q] = bf2f(s0[q]); acc[8 + q] = bf2f(s1[q]); }
    }

    int maxdeg = deg;
#pragma unroll
    for (int off = 16; off < 64; off <<= 1)
        maxdeg = max(maxdeg, __shfl_xor(maxdeg, off, 64));

    for (int it = 0; it < maxdeg; it += 4) {
        int4 g0 = {0,0,0,0}, g1 = {0,0,0,0}, g2 = {0,0,0,0}, g3 = {0,0,0,0};
        if (it < deg)
            g0 = *(const int4*)(feat_f8 + (size_t)csr_src[j + it] * HID + li * 16);
        if (it + 1 < deg)
            g1 = *(const int4*)(feat_f8 + (size_t)csr_src[j + it + 1] * HID + li * 16);
        if (it + 2 < deg)
            g2 = *(const int4*)(feat_f8 + (size_t)csr_src[j + it + 2] * HID + li * 16);
        if (it + 3 < deg)
            g3 = *(const int4*)(feat_f8 + (size_t)csr_src[j + it + 3] * HID + li * 16);
#pragma unroll
        for (int q = 0; q < 4; q++) {
            int w0 = (&g0.x)[q], w1 = (&g1.x)[q], w2 = (&g2.x)[q], w3 = (&g3.x)[q];
            f32x2 l0 = __builtin_amdgcn_cvt_pk_f32_fp8(w0, false);
            f32x2 h0 = __builtin_amdgcn_cvt_pk_f32_fp8(w0, true);
            f32x2 l1 = __builtin_amdgcn_cvt_pk_f32_fp8(w1, false);
            f32x2 h1 = __builtin_amdgcn_cvt_pk_f32_fp8(w1, true);
            f32x2 l2 = __builtin_amdgcn_cvt_pk_f32_fp8(w2, false);
            f32x2 h2 = __builtin_amdgcn_cvt_pk_f32_fp8(w2, true);
            f32x2 l3 = __builtin_amdgcn_cvt_pk_f32_fp8(w3, false);
            f32x2 h3 = __builtin_amdgcn_cvt_pk_f32_fp8(w3, true);
            acc[q * 4 + 0] += (l0.x + l1.x) + (l2.x + l3.x);
            acc[q * 4 + 1] += (l0.y + l1.y) + (l2.y + l3.y);
            acc[q * 4 + 2] += (h0.x + h1.x) + (h2.x + h3.x);
            acc[q * 4 + 3] += (h0.y + h1.y) + (h2.y + h3.y);
        }
    }

    u16x8 o0, o1;
#pragma unroll
    for (int q = 0; q < 8; q++) { o0[q] = f2bf(acc[q]); o1[q] = f2bf(acc[8 + q]); }
    *(u16x8*)(out + (size_t)node * HID + li * 16) = o0;
    *(u16x8*)(out + (size_t)node * HID + li * 16 + 8) = o1;
}

// ===========================================================================
// Fused 2-layer MLP. v12: TS pad (264) replaced by XOR-swizzled 256-stride
// t-tile -> LDS exactly 32 KB -> 5 blocks/CU (was 4). Swizzle involution
// (u16 idx ^= (row&7)<<3) applied at t-store, phase-2 read, epilogue store
// and repack read. Bank math: 2 lanes/bank on phase-2 reads = free.
// ===========================================================================
__global__ __launch_bounds__(256, 5) void mlp_fused(
    const u16* __restrict__ A, int K1,
    const u16* __restrict__ W1pk, const float* __restrict__ b1,
    const u16* __restrict__ W2pk, const float* __restrict__ b2,
    u16* __restrict__ out, u8* __restrict__ outF8, int M)
{
    __shared__ u16 SB[64 * 256];   // 32 KB: A-stage (phase1) then t-tile

    const int tid = threadIdx.x;
    const int lane = tid & 63;
    const int wid = tid >> 6;            // col-wave 0..3
    const int li = lane & 15;
    const int quad = lane >> 4;
    const int koff = quad * 8;
    const int row0 = blockIdx.x * 64;
    const int KB1 = K1 >> 5;             // 4 or 8 (even)
    const int rsh = (K1 == 256) ? 9 : 8;   // log2(row bytes)

    // ---- stage A tile 64 x K1 row-major, coalesced, inverse-swizzled src ----
    {
        const u8* Ag = (const u8*)(A + (size_t)row0 * K1);
        const int rounds = K1 >> 5;          // (64*K1*2)/4096
        for (int j = 0; j < rounds; j++) {
            int L = (j * 256 + tid) * 16;                 // LDS byte (lane-linear)
            int G = L ^ (((L >> rsh) & 7) << 4);          // involutive row-XOR
            async_cp16(Ag + G, (u8*)SB + L);
        }
    }

    f32x4 acc[4][4];
#pragma unroll
    for (int i = 0; i < 4; i++)
#pragma unroll
        for (int j = 0; j < 4; j++) acc[i][j] = (f32x4){0.f, 0.f, 0.f, 0.f};

#define LDW(WF, WPK, KB, KK32)                                                \
    {   _Pragma("unroll")                                                     \
        for (int t = 0; t < 4; t++)                                           \
            WF[t] = *(const bf16x8*)((WPK) +                                  \
                (((size_t)(wid * 4 + t) * (KB) + (KK32)) * 64 + lane) * 8); }
#define LDA1(AF, KK)                                                          \
    {   _Pragma("unroll")                                                     \
        for (int t = 0; t < 4; t++) {                                         \
            int row = t * 16 + li;                                            \
            int bo = row * (K1 * 2) + ((KK) + koff) * 2;                      \
            bo ^= (row & 7) << 4;                                             \
            AF[t] = *(const bf16x8*)((const u8*)SB + bo); } }
#define LDA2(AF, KK)                                                          \
    {   _Pragma("unroll")                                                     \
        for (int t = 0; t < 4; t++) {                                         \
            int row = t * 16 + li;                                            \
            int ix = (row * 256 + (KK) + koff) ^ ((row & 7) << 3);            \
            AF[t] = *(const bf16x8*)(SB + ix); } }
#define MFMA16(AF, WF)                                                        \
    {   _Pragma("unroll")                                                     \
        for (int mt = 0; mt < 4; mt++)                                        \
            _Pragma("unroll")                                                 \
            for (int nt = 0; nt < 4; nt++)                                    \
                acc[mt][nt] = __builtin_amdgcn_mfma_f32_16x16x32_bf16(        \
                    AF[mt], WF[nt], acc[mt][nt], 0, 0, 0); }

    bf16x8 wfA[4], wfB[4], af[4];

    // first W1 fragment: in flight across the staging drain
    LDW(wfA, W1pk, KB1, 0);
    __syncthreads();   // staging complete (implicit vmcnt drain)

    // ---- phase 1: t = A @ W1, W-loads pipelined one step ahead ----
    for (int kk32 = 0; kk32 < KB1; kk32 += 2) {
        LDW(wfB, W1pk, KB1, kk32 + 1);
        LDA1(af, kk32 * 32);
        MFMA16(af, wfA);
        if (kk32 + 2 < KB1) LDW(wfA, W1pk, KB1, kk32 + 2);
        LDA1(af, kk32 * 32 + 32);
        MFMA16(af, wfB);
    }
    __syncthreads();   // all A reads done; SB becomes the t-tile

    // bias+relu -> bf16 t-tile in LDS (swizzled u16 stores)
#pragma unroll
    for (int nt = 0; nt < 4; nt++) {
        int col = wid * 64 + nt * 16 + li;
        float bv = b1[col];
#pragma unroll
        for (int mt = 0; mt < 4; mt++) {
#pragma unroll
            for (int reg = 0; reg < 4; reg++) {
                int row = mt * 16 + quad * 4 + reg;
                float v = fmaxf(acc[mt][nt][reg] + bv, 0.f);
                SB[(row * 256 + col) ^ ((row & 7) << 3)] = f2bf(v);
                acc[mt][nt][reg] = 0.f;   // re-zero for phase 2
            }
        }
    }
    // first W2 fragment: in flight across the t-tile barrier
    LDW(wfA, W2pk, 8, 0);
    __syncthreads();

    // ---- phase 2: h = t @ W2, pipelined (HID/32 = 8 steps) ----
    for (int kk32 = 0; kk32 < 8; kk32 += 2) {
        LDW(wfB, W2pk, 8, kk32 + 1);
        LDA2(af, kk32 * 32);
        MFMA16(af, wfA);
        if (kk32 + 2 < 8) LDW(wfA, W2pk, 8, kk32 + 2);
        LDA2(af, kk32 * 32 + 32);
        MFMA16(af, wfB);
    }
#undef LDW
#undef LDA1
#undef LDA2
#undef MFMA16

    // ---- epilogue: bias+relu -> SB (swizzled), then contiguous stores ----
    __syncthreads();   // all phase-2 reads complete before overwrite
#pragma unroll
    for (int nt = 0; nt < 4; nt++) {
        int col = wid * 64 + nt * 16 + li;
        float bv = b2[col];
#pragma unroll
        for (int mt = 0; mt < 4; mt++) {
#pragma unroll
            for (int reg = 0; reg < 4; reg++) {
                int row = mt * 16 + quad * 4 + reg;
                float v = fmaxf(acc[mt][nt][reg] + bv, 0.f);
                SB[(row * 256 + col) ^ ((row & 7) << 3)] = f2bf(v);
            }
        }
    }
    __syncthreads();
    // flat repack: block output = 64 rows x 512 B = 32 KB contiguous
#pragma unroll
    for (int it = 0; it < 8; it++) {
        int flat = it * 4096 + tid * 16;      // byte offset in 64x512 tile
        int r = flat >> 9;                    // row within tile
        int cu = (flat & 511) >> 1;           // u16 col (multiple of 8)
        int row = row0 + r;
        if (row < M) {
            int ix = (r * 256 + cu) ^ ((r & 7) << 3);
            u16x8 v = *(const u16x8*)(SB + ix);
            *(u16x8*)(out + (size_t)row * HID + cu) = v;
            if (outF8 != nullptr) {
                int p0 = __builtin_amdgcn_cvt_pk_fp8_f32(bf2f(v[0]), bf2f(v[1]), 0, false);
                p0 = __builtin_amdgcn_cvt_pk_fp8_f32(bf2f(v[2]), bf2f(v[3]), p0, true);
                int p1 = __builtin_amdgcn_cvt_pk_fp8_f32(bf2f(v[4]), bf2f(v[5]), 0, false);
                p1 = __builtin_amdgcn_cvt_pk_fp8_f32(bf2f(v[6]), bf2f(v[7]), p1, true);
                int2 pv; pv.x = p0; pv.y = p1;
                *(int2*)(outF8 + (size_t)row * HID + cu) = pv;
            }
        }
    }
}

// ===========================================================================
// Final concat GEMM + fused log_softmax. v12: A halves (h1 then h2 — each a
// contiguous 64x256 u16 tile) staged via coalesced global_load_lds with
// both-sides XOR swizzle; fragments from LDS (kills the 16-segment per-lane
// A scatter). B stays fragment-packed-direct. 32 KB LDS -> 5 blocks/CU.
// ===========================================================================
__global__ __launch_bounds__(256, 5) void gemm_mfma(
    const u16* __restrict__ A, const u16* __restrict__ Acat,
    const u16* __restrict__ Bpk, const float* __restrict__ bias,
    float* __restrict__ out, int M)
{
    __shared__ u16 SA[64 * 256];   // 32 KB: one K-half of the 64-row A tile

    const int tid = threadIdx.x;
    const int lane = tid & 63;
    const int wid = tid >> 6;
    const int li = lane & 15;
    const int quad = lane >> 4;
    const int koff = quad * 8;
    const int row0 = blockIdx.x * 64;
    const int rloc = wid * 16 + li;    // this lane's A row within tile

    f32x4 acc[3];
#pragma unroll
    for (int i = 0; i < 3; i++) acc[i] = (f32x4){0.f, 0.f, 0.f, 0.f};

#define STAGE(SRC)                                                            \
    {   const u8* Ag = (const u8*)((SRC) + (size_t)row0 * 256);               \
        _Pragma("unroll")                                                     \
        for (int j = 0; j < 8; j++) {                                         \
            int L = (j * 256 + tid) * 16;                                     \
            int G = L ^ (((L >> 9) & 7) << 4);                                \
            async_cp16(Ag + G, (u8*)SA + L); } }
#define LDA_S(AF, KB32)                                                       \
    {   int bo = rloc * 512 + ((KB32) * 32 + koff) * 2;                       \
        bo ^= (rloc & 7) << 4;                                                \
        AF = *(const bf16x8*)((const u8*)SA + bo); }
#define LDB_S(BF, KK32)                                                       \
    {   _Pragma("unroll")                                                     \
        for (int t = 0; t < 3; t++)                                           \
            BF[t] = *(const bf16x8*)(Bpk +                                    \
                (((size_t)t * 16 + (KK32)) * 64 + lane) * 8); }
#define MFMA3(AF, BF)                                                         \
    {   _Pragma("unroll")                                                     \
        for (int nt = 0; nt < 3; nt++)                                        \
            acc[nt] = __builtin_amdgcn_mfma_f32_16x16x32_bf16(                \
                AF, BF[nt], acc[nt], 0, 0, 0); }

    bf16x8 a0, b0[3], a1, b1v[3];

    STAGE(A);                 // h1 half (kk32 0..7)
    LDB_S(b0, 0);
    __syncthreads();          // staging drained
    for (int k = 0; k < 8; k += 2) {
        LDB_S(b1v, k + 1);
        LDA_S(a0, k);
        MFMA3(a0, b0);
        if (k + 2 < 8) LDB_S(b0, k + 2);
        LDA_S(a1, k + 1);
        MFMA3(a1, b1v);
    }
    __syncthreads();          // all half-1 A reads done
    STAGE(Acat);              // h2 half (kk32 8..15)
    LDB_S(b0, 8);
    __syncthreads();
    for (int k = 8; k < 16; k += 2) {
        LDB_S(b1v, k + 1);
        LDA_S(a0, k - 8);
        MFMA3(a0, b0);
        if (k + 2 < 16) LDB_S(b0, k + 2);
        LDA_S(a1, k - 7);
        MFMA3(a1, b1v);
    }
#undef STAGE
#undef LDA_S
#undef LDB_S
#undef MFMA3

    float b0v = bias[li];
    float b1s = bias[16 + li];
    float b2s = (li < 8) ? bias[32 + li] : 0.f;
#pragma unroll
    for (int reg = 0; reg < 4; reg++) {
        int row = row0 + wid * 16 + quad * 4 + reg;
        float v0 = acc[0][reg] + b0v;
        float v1 = acc[1][reg] + b1s;
        float v2 = (li < 8) ? (acc[2][reg] + b2s) : -INFINITY;
        float m = fmaxf(fmaxf(v0, v1), v2);
#pragma unroll
        for (int off = 1; off < 16; off <<= 1)
            m = fmaxf(m, __shfl_xor(m, off, 64));
        float s = expf(v0 - m) + expf(v1 - m)
                + ((li < 8) ? expf(v2 - m) : 0.f);
#pragma unroll
        for (int off = 1; off < 16; off <<= 1)
            s += __shfl_xor(s, off, 64);
        float lg = m + logf(s);
        if (row < M) {
            out[(size_t)row * OUT_CH + li] = v0 - lg;
            out[(size_t)row * OUT_CH + 16 + li] = v1 - lg;
            if (li < 8) out[(size_t)row * OUT_CH + 32 + li] = v2 - lg;
        }
    }
}

// ---------------------------------------------------------------------------
extern "C" void kernel_launch(void* const* d_in, const int* in_sizes, int n_in,
                              void* d_out, int out_size, void* d_ws, size_t ws_size,
                              hipStream_t stream)
{
    const float* x    = (const float*)d_in[0];
    const int*   ei   = (const int*)d_in[1];
    const float* W1a  = (const float*)d_in[2];
    const float* b1a  = (const float*)d_in[3];
    const float* W2a  = (const float*)d_in[4];
    const float* b2a  = (const float*)d_in[5];
    const float* W1b  = (const float*)d_in[6];
    const float* b1b  = (const float*)d_in[7];
    const float* W2b  = (const float*)d_in[8];
    const float* b2b  = (const float*)d_in[9];
    const float* Wlin = (const float*)d_in[10];
    const float* blin = (const float*)d_in[11];
    float* out = (float*)d_out;

    // ---- workspace carve-up (regions of 50000*256 bf16 = 25.6 MB) ----
    const size_t R = (size_t)N_NODES * HID;
    u16* R0 = (u16*)d_ws;          // xbf
    u16* R1 = R0 + R;              // partial-hist / zA (1st half) + xf8 (2nd) -> h1f8
    u16* R2 = R1 + R;              // h2
    u16* R3 = R2 + R;              // h1 (live to end)
    u16* R4 = R3 + R;              // zB
    u16* xbf = R0;
    u16* zA  = R1;                                   // [50000,128] bf16
    u16* partial = (u16*)R1;                         // [256,6250] u16 (pre-gather_a)
    u8*  xf8 = (u8*)(R1 + (size_t)N_NODES * IN_CH);  // [50000,128] fp8
    u8*  h1f8 = (u8*)R1;                             // [50000,256] fp8 (rows written only
                                                     //  after the same rows of zA consumed)
    u16* h1  = R3;
    u16* zB  = R4;
    u16* h2  = R2;

    u16* wts = R4 + R;
    u16* W1aPk = wts;                      // 16 cb x 4 kk32 x 512 = 32768 u16
    u16* W2aPk = W1aPk + 256 * 128;        // 16 x 8 x 512 = 65536 u16
    u16* W1bPk = W2aPk + 256 * 256;
    u16* W2bPk = W1bPk + 256 * 256;
    u16* WlinPk = W2bPk + 256 * 256;       // 3 x 16 x 512 = 24576 u16
    int* rowp   = (int*)(WlinPk + 128 * 512);   // [N_NODES+1] (sentinel right after)
    int* part   = rowp + N_NODES + 64;          // [256] block partials
    u16* csr    = (u16*)(part + 256);      // [N_EDGES] u16 src ids
    u16* e16    = csr + N_EDGES;           // [2*N_EDGES] u16: src16 | dst16
    u16* src16  = e16;
    u16* dst16  = e16 + N_EDGES;
    u16* chunkpref = dst16 + N_EDGES;      // [NCHUNK][N_NODES] u16 = 3.2 MB

    dim3 blk(256);
    const int scanBlocks = (N_NODES + 255) / 256;    // 196
    const int agg128Blocks = (N_NODES + 31) / 32;    // 1563
    const int agg256Blocks = N_NODES / 16;           // 3125 (exact)
    const int mlpBlocks  = (N_NODES + 63) / 64;      // 782
    const int gemmBlocks = (N_NODES + 63) / 64;      // 782

    // ---- prep (+ absorbed histogram) + CSR build ----
    prep_fused<<<8392, blk, 0, stream>>>(x, xbf, xf8, ei, e16,
                                         W1a, W2a, W1b, W2b, Wlin,
                                         W1aPk, W2aPk, W1bPk, W2bPk, WlinPk,
                                         partial);
    scan1<<<scanBlocks, blk, 0, stream>>>(partial, chunkpref, rowp, part);
    scan3<<<scanBlocks, blk, 0, stream>>>(rowp, part, rowp + N_NODES, scanBlocks);
    csr_fill<<<16 * NCHUNK, blk, 0, stream>>>(src16, dst16, rowp, chunkpref, csr);

    // ---- Layer a: gather + fused MLP (zA -> h1, + fp8 table) ----
    gather_agg_f8_128<<<agg128Blocks, blk, 0, stream>>>(xbf, xf8, rowp, rowp + 1, csr, zA);
    mlp_fused<<<mlpBlocks, blk, 0, stream>>>(zA, IN_CH, W1aPk, b1a, W2aPk, b2a,
                                             h1, h1f8, N_NODES);

    // ---- Layer b: gather + fused MLP (zB -> h2) ----
    gather_agg_f8_256<<<agg256Blocks, blk, 0, stream>>>(h1, h1f8, rowp, rowp + 1, csr, zB);
    mlp_fused<<<mlpBlocks, blk, 0, stream>>>(zB, HID, W1bPk, b1b, W2bPk, b2b,
                                             h2, nullptr, N_NODES);

    // ---- Final linear on [h1 | h2] + fused log_softmax -> d_out ----
    gemm_mfma<<<gemmBlocks, blk, 0, stream>>>(h1, h2, WlinPk, blin, out, N_NODES);
}

// Round 13
// 251.850 us; speedup vs baseline: 1.6520x; 1.6520x over previous
//
#include <hip/hip_runtime.h>
#include <math.h>

// Problem constants
#define N_NODES 50000
#define N_EDGES 800000
#define IN_CH 128
#define HID 256
#define OUT_CH 40
#define GRP 6250          // nodes per dst-group (8 groups)
#define HGRP 3125         // half-group window: 16 windows x 32 chunks = 512 blocks
#define NCHUNK 32         // edge-chunks
#define TS 264            // LDS t-tile row stride (u16): 256+8 breaks bank pow2

typedef unsigned short u16;
typedef unsigned char u8;
typedef __attribute__((ext_vector_type(8))) short bf16x8;
typedef __attribute__((ext_vector_type(8))) unsigned short u16x8;
typedef __attribute__((ext_vector_type(4))) float f32x4;
typedef __attribute__((ext_vector_type(2))) float f32x2;

__device__ __forceinline__ float bf2f(u16 u) {
    union { unsigned int i; float f; } v; v.i = ((unsigned int)u) << 16; return v.f;
}
__device__ __forceinline__ u16 f2bf(float f) {   // round-to-nearest-even
    union { float f; unsigned int i; } v; v.f = f;
    unsigned int x = v.i;
    x += 0x7fffu + ((x >> 16) & 1u);
    return (u16)(x >> 16);
}

#define GLOBAL_AS __attribute__((address_space(1)))
#define LDS_AS __attribute__((address_space(3)))
__device__ __forceinline__ void async_cp16(const void* g, void* l) {
    __builtin_amdgcn_global_load_lds((const GLOBAL_AS unsigned int*)g,
                                     (LDS_AS unsigned int*)l, 16, 0, 0);
}

// ===========================================================================
// Fused prep: x->{bf16,fp8} + weight packing + u16 edge copies + the
// degree histogram (reads dst straight from the int32 edge_index).
// Block ranges: [0,6250) conv_x; [6250,7813) edge-compress; [7813,7880)
// weight-pack; [7880,8392) histogram (16 half-group windows x 32 chunks).
// ===========================================================================
__device__ __forceinline__ void pack_w(
    const float* __restrict__ in, u16* __restrict__ out, int K, int N, int c)
{
    for (int k = threadIdx.x; k < K; k += 256) {
        int kk32 = k >> 5, quad = (k >> 3) & 3, e = k & 7;
        size_t base = (((size_t)c * (K >> 5) + kk32) * 64 + quad * 16) * 8 + e;
#pragma unroll
        for (int li = 0; li < 16; li++) {
            int n = c * 16 + li;
            float v = (n < N) ? in[(size_t)k * N + n] : 0.f;
            out[base + (size_t)li * 8] = f2bf(v);
        }
    }
}

__global__ __launch_bounds__(256) void prep_fused(
    const float* __restrict__ x, u16* __restrict__ xb, u8* __restrict__ xf8,
    const int* __restrict__ ei, u16* __restrict__ e16,
    const float* __restrict__ W1a, const float* __restrict__ W2a,
    const float* __restrict__ W1b, const float* __restrict__ W2b,
    const float* __restrict__ Wlin,
    u16* __restrict__ W1aPk, u16* __restrict__ W2aPk,
    u16* __restrict__ W1bPk, u16* __restrict__ W2bPk, u16* __restrict__ WlinPk,
    u16* __restrict__ partial)
{
    __shared__ int hist[HGRP];     // 12.5 KB (used only by histogram blocks)
    int b = blockIdx.x;
    if (b < 6250) {
        int i = b * 256 + threadIdx.x;
        float4 v = ((const float4*)x)[i];
        ushort4 o;
        o.x = f2bf(v.x); o.y = f2bf(v.y); o.z = f2bf(v.z); o.w = f2bf(v.w);
        ((ushort4*)xb)[i] = o;
        int p = __builtin_amdgcn_cvt_pk_fp8_f32(v.x, v.y, 0, false);
        p = __builtin_amdgcn_cvt_pk_fp8_f32(v.z, v.w, p, true);
        ((unsigned int*)xf8)[i] = (unsigned int)p;
    } else if (b < 7813) {
        int i = (b - 6250) * 256 + threadIdx.x;
        if (i < (2 * N_EDGES) / 4) {
            int4 v = ((const int4*)ei)[i];
            ushort4 o;
            o.x = (u16)v.x; o.y = (u16)v.y; o.z = (u16)v.z; o.w = (u16)v.w;
            ((ushort4*)e16)[i] = o;
        }
    } else if (b < 7880) {
        int t = b - 7813;
        if (t < 16)       pack_w(W1a, W1aPk, IN_CH, HID, t);
        else if (t < 32)  pack_w(W2a, W2aPk, HID, HID, t - 16);
        else if (t < 48)  pack_w(W1b, W1bPk, HID, HID, t - 32);
        else if (t < 64)  pack_w(W2b, W2bPk, HID, HID, t - 48);
        else              pack_w(Wlin, WlinPk, 2 * HID, OUT_CH, t - 64);
    } else {
        // ---- degree histogram, straight from int32 dst ----
        const int hb = b - 7880;           // [0,512)
        const int gh = hb & 15;
        const int sub = hb >> 4;
        const int lo = gh * HGRP;
        const int CH = N_EDGES / NCHUNK;   // 25000
        for (int i = threadIdx.x; i < HGRP; i += 256) hist[i] = 0;
        __syncthreads();
        const int4* dsts = (const int4*)(ei + N_EDGES + sub * CH);
        for (int k = threadIdx.x; k < CH / 4; k += 256) {
            int4 d = dsts[k];
            int r0 = d.x - lo, r1 = d.y - lo;
            int r2 = d.z - lo, r3 = d.w - lo;
            if ((unsigned)r0 < (unsigned)HGRP) atomicAdd(&hist[r0], 1);
            if ((unsigned)r1 < (unsigned)HGRP) atomicAdd(&hist[r1], 1);
            if ((unsigned)r2 < (unsigned)HGRP) atomicAdd(&hist[r2], 1);
            if ((unsigned)r3 < (unsigned)HGRP) atomicAdd(&hist[r3], 1);
        }
        __syncthreads();
        u16* po = partial + (size_t)(sub * 8 + (gh >> 1)) * GRP + (gh & 1) * HGRP;
        for (int i = threadIdx.x; i < HGRP; i += 256) po[i] = (u16)hist[i];
    }
}

// ===========================================================================
// scan1 (absorbs deg_cp): 196 blocks, one node per thread.
// ===========================================================================
__global__ __launch_bounds__(256) void scan1(
    const u16* __restrict__ partial, u16* __restrict__ chunkpref,
    int* __restrict__ excl, int* __restrict__ partials_out)
{
    __shared__ int lds[256];
    const int tid = threadIdx.x;
    const int node = blockIdx.x * 256 + tid;
    int d = 0;
    if (node < N_NODES) {
        int g = node / GRP;
        int off = node - g * GRP;
#pragma unroll
        for (int sub = 0; sub < NCHUNK; sub++) {
            chunkpref[(size_t)sub * N_NODES + node] = (u16)d;   // exclusive
            d += partial[(size_t)(sub * 8 + g) * GRP + off];
        }
    }
    lds[tid] = d;
    __syncthreads();
    for (int off = 1; off < 256; off <<= 1) {
        int t = (tid >= off) ? lds[tid - off] : 0;
        __syncthreads();
        lds[tid] += t;
        __syncthreads();
    }
    if (node < N_NODES) excl[node] = lds[tid] - d;
    if (tid == 255) partials_out[blockIdx.x] = lds[255];
}

// ===========================================================================
// scan3: add block prefixes (196 partials, 256-wide scan) + sentinel.
// ===========================================================================
__global__ __launch_bounds__(256) void scan3(
    int* __restrict__ excl, const int* __restrict__ partials,
    int* __restrict__ sentinel, int nPart)
{
    __shared__ int lds[256];
    __shared__ int bp[256];
    const int tid = threadIdx.x;
    int orig = (tid < nPart) ? partials[tid] : 0;
    lds[tid] = orig;
    __syncthreads();
    for (int off = 1; off < 256; off <<= 1) {
        int t = (tid >= off) ? lds[tid - off] : 0;
        __syncthreads();
        lds[tid] += t;
        __syncthreads();
    }
    bp[tid] = lds[tid] - orig;
    __syncthreads();
    const int idx = blockIdx.x * 256 + tid;
    if (idx < N_NODES) excl[idx] += bp[blockIdx.x];
    if (idx == 0) sentinel[0] = N_EDGES;   // rowp[N_NODES] = N_EDGES
}

// ===========================================================================
// csr_fill: atomic-FREE placement, half-group windows (512 blocks, 2/CU).
// ===========================================================================
__global__ __launch_bounds__(256) void csr_fill(
    const u16* __restrict__ src16, const u16* __restrict__ dst16,
    const int* __restrict__ rowp, const u16* __restrict__ chunkpref,
    u16* __restrict__ csr_src)
{
    __shared__ int cur[HGRP];     // 12.5 KB
    const int gh = blockIdx.x & 15;
    const int c = blockIdx.x >> 4;
    const int lo = gh * HGRP;
    const int CH = N_EDGES / NCHUNK;          // 25000
    const u16* cp = chunkpref + (size_t)c * N_NODES + lo;
    for (int i = threadIdx.x; i < HGRP; i += 256)
        cur[i] = rowp[lo + i] + cp[i];
    __syncthreads();
    const ushort4* dsts = (const ushort4*)(dst16 + c * CH);
    const ushort4* srcs = (const ushort4*)(src16 + c * CH);
    for (int k = threadIdx.x; k < CH / 4; k += 256) {
        ushort4 d = dsts[k];
        ushort4 sc = srcs[k];
        int r0 = (int)d.x - lo, r1 = (int)d.y - lo;
        int r2 = (int)d.z - lo, r3 = (int)d.w - lo;
        if ((unsigned)r0 < (unsigned)HGRP) { int p = atomicAdd(&cur[r0], 1); csr_src[p] = sc.x; }
        if ((unsigned)r1 < (unsigned)HGRP) { int p = atomicAdd(&cur[r1], 1); csr_src[p] = sc.y; }
        if ((unsigned)r2 < (unsigned)HGRP) { int p = atomicAdd(&cur[r2], 1); csr_src[p] = sc.z; }
        if ((unsigned)r3 < (unsigned)HGRP) { int p = atomicAdd(&cur[r3], 1); csr_src[p] = sc.w; }
    }
}

// ===========================================================================
// Gather aggregation: wide per-edge gathers (16B/lane dwordx4), unroll x4.
// ===========================================================================

// IN_CH=128: 8 lanes/node (16B/lane), 8 nodes/wave, 32 nodes/block.
__global__ __launch_bounds__(256) void gather_agg_f8_128(
    const u16* __restrict__ feat_bf, const u8* __restrict__ feat_f8,
    const int* __restrict__ row_ptr, const int* __restrict__ row_end,
    const u16* __restrict__ csr_src, u16* __restrict__ out)
{
    const int tid = threadIdx.x;
    const int lane = tid & 63;
    const int wv = tid >> 6;
    const int li = lane & 7;
    int node = blockIdx.x * 32 + wv * 8 + (lane >> 3);
    const bool valid = node < N_NODES;
    if (!valid) node = N_NODES - 1;

    int j = row_ptr[node];
    int deg = valid ? (row_end[node] - j) : 0;

    float acc[16];
    {
        u16x8 s0 = *(const u16x8*)(feat_bf + (size_t)node * IN_CH + li * 16);
        u16x8 s1 = *(const u16x8*)(feat_bf + (size_t)node * IN_CH + li * 16 + 8);
#pragma unroll
        for (int q = 0; q < 8; q++) { acc[q] = bf2f(s0[q]); acc[8 + q] = bf2f(s1[q]); }
    }

    int maxdeg = deg;
#pragma unroll
    for (int off = 8; off < 64; off <<= 1)
        maxdeg = max(maxdeg, __shfl_xor(maxdeg, off, 64));

    for (int it = 0; it < maxdeg; it += 4) {
        int4 g0 = {0,0,0,0}, g1 = {0,0,0,0}, g2 = {0,0,0,0}, g3 = {0,0,0,0};
        if (it < deg)
            g0 = *(const int4*)(feat_f8 + (size_t)csr_src[j + it] * IN_CH + li * 16);
        if (it + 1 < deg)
            g1 = *(const int4*)(feat_f8 + (size_t)csr_src[j + it + 1] * IN_CH + li * 16);
        if (it + 2 < deg)
            g2 = *(const int4*)(feat_f8 + (size_t)csr_src[j + it + 2] * IN_CH + li * 16);
        if (it + 3 < deg)
            g3 = *(const int4*)(feat_f8 + (size_t)csr_src[j + it + 3] * IN_CH + li * 16);
#pragma unroll
        for (int q = 0; q < 4; q++) {
            int w0 = (&g0.x)[q], w1 = (&g1.x)[q], w2 = (&g2.x)[q], w3 = (&g3.x)[q];
            f32x2 l0 = __builtin_amdgcn_cvt_pk_f32_fp8(w0, false);
            f32x2 h0 = __builtin_amdgcn_cvt_pk_f32_fp8(w0, true);
            f32x2 l1 = __builtin_amdgcn_cvt_pk_f32_fp8(w1, false);
            f32x2 h1 = __builtin_amdgcn_cvt_pk_f32_fp8(w1, true);
            f32x2 l2 = __builtin_amdgcn_cvt_pk_f32_fp8(w2, false);
            f32x2 h2 = __builtin_amdgcn_cvt_pk_f32_fp8(w2, true);
            f32x2 l3 = __builtin_amdgcn_cvt_pk_f32_fp8(w3, false);
            f32x2 h3 = __builtin_amdgcn_cvt_pk_f32_fp8(w3, true);
            acc[q * 4 + 0] += (l0.x + l1.x) + (l2.x + l3.x);
            acc[q * 4 + 1] += (l0.y + l1.y) + (l2.y + l3.y);
            acc[q * 4 + 2] += (h0.x + h1.x) + (h2.x + h3.x);
            acc[q * 4 + 3] += (h0.y + h1.y) + (h2.y + h3.y);
        }
    }

    if (valid) {
        u16x8 o0, o1;
#pragma unroll
        for (int q = 0; q < 8; q++) { o0[q] = f2bf(acc[q]); o1[q] = f2bf(acc[8 + q]); }
        *(u16x8*)(out + (size_t)node * IN_CH + li * 16) = o0;
        *(u16x8*)(out + (size_t)node * IN_CH + li * 16 + 8) = o1;
    }
}

// HID=256: 16 lanes/node (16B/lane), 4 nodes/wave, 16 nodes/block (no tail).
__global__ __launch_bounds__(256) void gather_agg_f8_256(
    const u16* __restrict__ feat_bf, const u8* __restrict__ feat_f8,
    const int* __restrict__ row_ptr, const int* __restrict__ row_end,
    const u16* __restrict__ csr_src, u16* __restrict__ out)
{
    const int tid = threadIdx.x;
    const int lane = tid & 63;
    const int wv = tid >> 6;
    const int li = lane & 15;
    const int node = blockIdx.x * 16 + wv * 4 + (lane >> 4);   // 3125*16 = 50000

    int j = row_ptr[node];
    int deg = row_end[node] - j;

    float acc[16];
    {
        u16x8 s0 = *(const u16x8*)(feat_bf + (size_t)node * HID + li * 16);
        u16x8 s1 = *(const u16x8*)(feat_bf + (size_t)node * HID + li * 16 + 8);
#pragma unroll
        for (int q = 0; q < 8; q++) { acc[q] = bf2f(s0[q]); acc[8 + q] = bf2f(s1[q]); }
    }

    int maxdeg = deg;
#pragma unroll
    for (int off = 16; off < 64; off <<= 1)
        maxdeg = max(maxdeg, __shfl_xor(maxdeg, off, 64));

    for (int it = 0; it < maxdeg; it += 4) {
        int4 g0 = {0,0,0,0}, g1 = {0,0,0,0}, g2 = {0,0,0,0}, g3 = {0,0,0,0};
        if (it < deg)
            g0 = *(const int4*)(feat_f8 + (size_t)csr_src[j + it] * HID + li * 16);
        if (it + 1 < deg)
            g1 = *(const int4*)(feat_f8 + (size_t)csr_src[j + it + 1] * HID + li * 16);
        if (it + 2 < deg)
            g2 = *(const int4*)(feat_f8 + (size_t)csr_src[j + it + 2] * HID + li * 16);
        if (it + 3 < deg)
            g3 = *(const int4*)(feat_f8 + (size_t)csr_src[j + it + 3] * HID + li * 16);
#pragma unroll
        for (int q = 0; q < 4; q++) {
            int w0 = (&g0.x)[q], w1 = (&g1.x)[q], w2 = (&g2.x)[q], w3 = (&g3.x)[q];
            f32x2 l0 = __builtin_amdgcn_cvt_pk_f32_fp8(w0, false);
            f32x2 h0 = __builtin_amdgcn_cvt_pk_f32_fp8(w0, true);
            f32x2 l1 = __builtin_amdgcn_cvt_pk_f32_fp8(w1, false);
            f32x2 h1 = __builtin_amdgcn_cvt_pk_f32_fp8(w1, true);
            f32x2 l2 = __builtin_amdgcn_cvt_pk_f32_fp8(w2, false);
            f32x2 h2 = __builtin_amdgcn_cvt_pk_f32_fp8(w2, true);
            f32x2 l3 = __builtin_amdgcn_cvt_pk_f32_fp8(w3, false);
            f32x2 h3 = __builtin_amdgcn_cvt_pk_f32_fp8(w3, true);
            acc[q * 4 + 0] += (l0.x + l1.x) + (l2.x + l3.x);
            acc[q * 4 + 1] += (l0.y + l1.y) + (l2.y + l3.y);
            acc[q * 4 + 2] += (h0.x + h1.x) + (h2.x + h3.x);
            acc[q * 4 + 3] += (h0.y + h1.y) + (h2.y + h3.y);
        }
    }

    u16x8 o0, o1;
#pragma unroll
    for (int q = 0; q < 8; q++) { o0[q] = f2bf(acc[q]); o1[q] = f2bf(acc[8 + q]); }
    *(u16x8*)(out + (size_t)node * HID + li * 16) = o0;
    *(u16x8*)(out + (size_t)node * HID + li * 16 + 8) = o1;
}

// ===========================================================================
// Fused 2-layer MLP — R11 version restored EXACTLY (TS=264 pad, bounds
// (256,4), 33 KB LDS). R12's (256,5) + 32KB swizzle spilled the 64-VGPR
// accumulator to scratch (VGPR_Count 48, WRITE_SIZE 245 MB, 113 µs).
// Occupancy lever rejected: spill cost >> TLP gain.
// ===========================================================================
__global__ __launch_bounds__(256, 4) void mlp_fused(
    const u16* __restrict__ A, int K1,
    const u16* __restrict__ W1pk, const float* __restrict__ b1,
    const u16* __restrict__ W2pk, const float* __restrict__ b2,
    u16* __restrict__ out, u8* __restrict__ outF8, int M)
{
    __shared__ u16 SB[64 * TS];   // 33 KB: A-stage (phase1) then t-tile

    const int tid = threadIdx.x;
    const int lane = tid & 63;
    const int wid = tid >> 6;            // col-wave 0..3
    const int li = lane & 15;
    const int quad = lane >> 4;
    const int koff = quad * 8;
    const int row0 = blockIdx.x * 64;
    const int KB1 = K1 >> 5;             // 4 or 8 (even)
    const int rsh = (K1 == 256) ? 9 : 8;   // log2(row bytes)

    // ---- stage A tile 64 x K1 row-major, coalesced, inverse-swizzled src ----
    {
        const u8* Ag = (const u8*)(A + (size_t)row0 * K1);
        const int rounds = K1 >> 5;          // (64*K1*2)/4096
        for (int j = 0; j < rounds; j++) {
            int L = (j * 256 + tid) * 16;                 // LDS byte (lane-linear)
            int G = L ^ (((L >> rsh) & 7) << 4);          // involutive row-XOR
            async_cp16(Ag + G, (u8*)SB + L);
        }
    }

    f32x4 acc[4][4];
#pragma unroll
    for (int i = 0; i < 4; i++)
#pragma unroll
        for (int j = 0; j < 4; j++) acc[i][j] = (f32x4){0.f, 0.f, 0.f, 0.f};

#define LDW(WF, WPK, KB, KK32)                                                \
    {   _Pragma("unroll")                                                     \
        for (int t = 0; t < 4; t++)                                           \
            WF[t] = *(const bf16x8*)((WPK) +                                  \
                (((size_t)(wid * 4 + t) * (KB) + (KK32)) * 64 + lane) * 8); }
#define LDA1(AF, KK)                                                          \
    {   _Pragma("unroll")                                                     \
        for (int t = 0; t < 4; t++) {                                         \
            int row = t * 16 + li;                                            \
            int bo = row * (K1 * 2) + ((KK) + koff) * 2;                      \
            bo ^= (row & 7) << 4;                                             \
            AF[t] = *(const bf16x8*)((const u8*)SB + bo); } }
#define LDA2(AF, KK)                                                          \
    {   _Pragma("unroll")                                                     \
        for (int t = 0; t < 4; t++)                                           \
            AF[t] = *(const bf16x8*)(SB + (t * 16 + li) * TS + (KK) + koff); }
#define MFMA16(AF, WF)                                                        \
    {   _Pragma("unroll")                                                     \
        for (int mt = 0; mt < 4; mt++)                                        \
            _Pragma("unroll")                                                 \
            for (int nt = 0; nt < 4; nt++)                                    \
                acc[mt][nt] = __builtin_amdgcn_mfma_f32_16x16x32_bf16(        \
                    AF[mt], WF[nt], acc[mt][nt], 0, 0, 0); }

    bf16x8 wfA[4], wfB[4], af[4];

    // first W1 fragment: in flight across the staging drain
    LDW(wfA, W1pk, KB1, 0);
    __syncthreads();   // staging complete (implicit vmcnt drain)

    // ---- phase 1: t = A @ W1, W-loads pipelined one step ahead ----
    for (int kk32 = 0; kk32 < KB1; kk32 += 2) {
        LDW(wfB, W1pk, KB1, kk32 + 1);
        LDA1(af, kk32 * 32);
        MFMA16(af, wfA);
        if (kk32 + 2 < KB1) LDW(wfA, W1pk, KB1, kk32 + 2);
        LDA1(af, kk32 * 32 + 32);
        MFMA16(af, wfB);
    }
    __syncthreads();   // all A reads done; SB becomes the t-tile

    // bias+relu -> bf16 t-tile in LDS (C/D layout scatter; u16 stores)
#pragma unroll
    for (int nt = 0; nt < 4; nt++) {
        int col = wid * 64 + nt * 16 + li;
        float bv = b1[col];
#pragma unroll
        for (int mt = 0; mt < 4; mt++) {
#pragma unroll
            for (int reg = 0; reg < 4; reg++) {
                int row = mt * 16 + quad * 4 + reg;
                float v = fmaxf(acc[mt][nt][reg] + bv, 0.f);
                SB[row * TS + col] = f2bf(v);
                acc[mt][nt][reg] = 0.f;   // re-zero for phase 2
            }
        }
    }
    // first W2 fragment: in flight across the t-tile barrier
    LDW(wfA, W2pk, 8, 0);
    __syncthreads();

    // ---- phase 2: h = t @ W2, pipelined (HID/32 = 8 steps) ----
    for (int kk32 = 0; kk32 < 8; kk32 += 2) {
        LDW(wfB, W2pk, 8, kk32 + 1);
        LDA2(af, kk32 * 32);
        MFMA16(af, wfA);
        if (kk32 + 2 < 8) LDW(wfA, W2pk, 8, kk32 + 2);
        LDA2(af, kk32 * 32 + 32);
        MFMA16(af, wfB);
    }
#undef LDW
#undef LDA1
#undef LDA2
#undef MFMA16

    // ---- epilogue: bias+relu -> SB, then vectorized contiguous stores ----
    __syncthreads();   // all phase-2 reads complete before overwrite
#pragma unroll
    for (int nt = 0; nt < 4; nt++) {
        int col = wid * 64 + nt * 16 + li;
        float bv = b2[col];
#pragma unroll
        for (int mt = 0; mt < 4; mt++) {
#pragma unroll
            for (int reg = 0; reg < 4; reg++) {
                int row = mt * 16 + quad * 4 + reg;
                float v = fmaxf(acc[mt][nt][reg] + bv, 0.f);
                SB[row * TS + col] = f2bf(v);
            }
        }
    }
    __syncthreads();
    // flat repack: block output = 64 rows x 512 B = 32 KB contiguous
#pragma unroll
    for (int it = 0; it < 8; it++) {
        int flat = it * 4096 + tid * 16;      // byte offset in 64x512 tile
        int r = flat >> 9;                    // row within tile
        int cu = (flat & 511) >> 1;           // u16 col
        int row = row0 + r;
        if (row < M) {
            u16x8 v = *(const u16x8*)(SB + r * TS + cu);
            *(u16x8*)(out + (size_t)row * HID + cu) = v;
            if (outF8 != nullptr) {
                int p0 = __builtin_amdgcn_cvt_pk_fp8_f32(bf2f(v[0]), bf2f(v[1]), 0, false);
                p0 = __builtin_amdgcn_cvt_pk_fp8_f32(bf2f(v[2]), bf2f(v[3]), p0, true);
                int p1 = __builtin_amdgcn_cvt_pk_fp8_f32(bf2f(v[4]), bf2f(v[5]), 0, false);
                p1 = __builtin_amdgcn_cvt_pk_fp8_f32(bf2f(v[6]), bf2f(v[7]), p1, true);
                int2 pv; pv.x = p0; pv.y = p1;
                *(int2*)(outF8 + (size_t)row * HID + cu) = pv;
            }
        }
    }
}

// ===========================================================================
// Final concat GEMM + fused log_softmax (v12: LDS-staged A halves, small
// register footprint so bounds(256,5) is spill-safe).
// ===========================================================================
__global__ __launch_bounds__(256, 5) void gemm_mfma(
    const u16* __restrict__ A, const u16* __restrict__ Acat,
    const u16* __restrict__ Bpk, const float* __restrict__ bias,
    float* __restrict__ out, int M)
{
    __shared__ u16 SA[64 * 256];   // 32 KB: one K-half of the 64-row A tile

    const int tid = threadIdx.x;
    const int lane = tid & 63;
    const int wid = tid >> 6;
    const int li = lane & 15;
    const int quad = lane >> 4;
    const int koff = quad * 8;
    const int row0 = blockIdx.x * 64;
    const int rloc = wid * 16 + li;    // this lane's A row within tile

    f32x4 acc[3];
#pragma unroll
    for (int i = 0; i < 3; i++) acc[i] = (f32x4){0.f, 0.f, 0.f, 0.f};

#define STAGE(SRC)                                                            \
    {   const u8* Ag = (const u8*)((SRC) + (size_t)row0 * 256);               \
        _Pragma("unroll")                                                     \
        for (int j = 0; j < 8; j++) {                                         \
            int L = (j * 256 + tid) * 16;                                     \
            int G = L ^ (((L >> 9) & 7) << 4);                                \
            async_cp16(Ag + G, (u8*)SA + L); } }
#define LDA_S(AF, KB32)                                                       \
    {   int bo = rloc * 512 + ((KB32) * 32 + koff) * 2;                       \
        bo ^= (rloc & 7) << 4;                                                \
        AF = *(const bf16x8*)((const u8*)SA + bo); }
#define LDB_S(BF, KK32)                                                       \
    {   _Pragma("unroll")                                                     \
        for (int t = 0; t < 3; t++)                                           \
            BF[t] = *(const bf16x8*)(Bpk +                                    \
                (((size_t)t * 16 + (KK32)) * 64 + lane) * 8); }
#define MFMA3(AF, BF)                                                         \
    {   _Pragma("unroll")                                                     \
        for (int nt = 0; nt < 3; nt++)                                        \
            acc[nt] = __builtin_amdgcn_mfma_f32_16x16x32_bf16(                \
                AF, BF[nt], acc[nt], 0, 0, 0); }

    bf16x8 a0, b0[3], a1, b1v[3];

    STAGE(A);                 // h1 half (kk32 0..7)
    LDB_S(b0, 0);
    __syncthreads();          // staging drained
    for (int k = 0; k < 8; k += 2) {
        LDB_S(b1v, k + 1);
        LDA_S(a0, k);
        MFMA3(a0, b0);
        if (k + 2 < 8) LDB_S(b0, k + 2);
        LDA_S(a1, k + 1);
        MFMA3(a1, b1v);
    }
    __syncthreads();          // all half-1 A reads done
    STAGE(Acat);              // h2 half (kk32 8..15)
    LDB_S(b0, 8);
    __syncthreads();
    for (int k = 8; k < 16; k += 2) {
        LDB_S(b1v, k + 1);
        LDA_S(a0, k - 8);
        MFMA3(a0, b0);
        if (k + 2 < 16) LDB_S(b0, k + 2);
        LDA_S(a1, k - 7);
        MFMA3(a1, b1v);
    }
#undef STAGE
#undef LDA_S
#undef LDB_S
#undef MFMA3

    float b0v = bias[li];
    float b1s = bias[16 + li];
    float b2s = (li < 8) ? bias[32 + li] : 0.f;
#pragma unroll
    for (int reg = 0; reg < 4; reg++) {
        int row = row0 + wid * 16 + quad * 4 + reg;
        float v0 = acc[0][reg] + b0v;
        float v1 = acc[1][reg] + b1s;
        float v2 = (li < 8) ? (acc[2][reg] + b2s) : -INFINITY;
        float m = fmaxf(fmaxf(v0, v1), v2);
#pragma unroll
        for (int off = 1; off < 16; off <<= 1)
            m = fmaxf(m, __shfl_xor(m, off, 64));
        float s = expf(v0 - m) + expf(v1 - m)
                + ((li < 8) ? expf(v2 - m) : 0.f);
#pragma unroll
        for (int off = 1; off < 16; off <<= 1)
            s += __shfl_xor(s, off, 64);
        float lg = m + logf(s);
        if (row < M) {
            out[(size_t)row * OUT_CH + li] = v0 - lg;
            out[(size_t)row * OUT_CH + 16 + li] = v1 - lg;
            if (li < 8) out[(size_t)row * OUT_CH + 32 + li] = v2 - lg;
        }
    }
}

// ---------------------------------------------------------------------------
extern "C" void kernel_launch(void* const* d_in, const int* in_sizes, int n_in,
                              void* d_out, int out_size, void* d_ws, size_t ws_size,
                              hipStream_t stream)
{
    const float* x    = (const float*)d_in[0];
    const int*   ei   = (const int*)d_in[1];
    const float* W1a  = (const float*)d_in[2];
    const float* b1a  = (const float*)d_in[3];
    const float* W2a  = (const float*)d_in[4];
    const float* b2a  = (const float*)d_in[5];
    const float* W1b  = (const float*)d_in[6];
    const float* b1b  = (const float*)d_in[7];
    const float* W2b  = (const float*)d_in[8];
    const float* b2b  = (const float*)d_in[9];
    const float* Wlin = (const float*)d_in[10];
    const float* blin = (const float*)d_in[11];
    float* out = (float*)d_out;

    // ---- workspace carve-up (regions of 50000*256 bf16 = 25.6 MB) ----
    const size_t R = (size_t)N_NODES * HID;
    u16* R0 = (u16*)d_ws;          // xbf
    u16* R1 = R0 + R;              // partial-hist / zA (1st half) + xf8 (2nd) -> h1f8
    u16* R2 = R1 + R;              // h2
    u16* R3 = R2 + R;              // h1 (live to end)
    u16* R4 = R3 + R;              // zB
    u16* xbf = R0;
    u16* zA  = R1;                                   // [50000,128] bf16
    u16* partial = (u16*)R1;                         // [256,6250] u16 (pre-gather_a)
    u8*  xf8 = (u8*)(R1 + (size_t)N_NODES * IN_CH);  // [50000,128] fp8
    u8*  h1f8 = (u8*)R1;                             // [50000,256] fp8 (rows written only
                                                     //  after the same rows of zA consumed)
    u16* h1  = R3;
    u16* zB  = R4;
    u16* h2  = R2;

    u16* wts = R4 + R;
    u16* W1aPk = wts;                      // 16 cb x 4 kk32 x 512 = 32768 u16
    u16* W2aPk = W1aPk + 256 * 128;        // 16 x 8 x 512 = 65536 u16
    u16* W1bPk = W2aPk + 256 * 256;
    u16* W2bPk = W1bPk + 256 * 256;
    u16* WlinPk = W2bPk + 256 * 256;       // 3 x 16 x 512 = 24576 u16
    int* rowp   = (int*)(WlinPk + 128 * 512);   // [N_NODES+1] (sentinel right after)
    int* part   = rowp + N_NODES + 64;          // [256] block partials
    u16* csr    = (u16*)(part + 256);      // [N_EDGES] u16 src ids
    u16* e16    = csr + N_EDGES;           // [2*N_EDGES] u16: src16 | dst16
    u16* src16  = e16;
    u16* dst16  = e16 + N_EDGES;
    u16* chunkpref = dst16 + N_EDGES;      // [NCHUNK][N_NODES] u16 = 3.2 MB

    dim3 blk(256);
    const int scanBlocks = (N_NODES + 255) / 256;    // 196
    const int agg128Blocks = (N_NODES + 31) / 32;    // 1563
    const int agg256Blocks = N_NODES / 16;           // 3125 (exact)
    const int mlpBlocks  = (N_NODES + 63) / 64;      // 782
    const int gemmBlocks = (N_NODES + 63) / 64;      // 782

    // ---- prep (+ absorbed histogram) + CSR build ----
    prep_fused<<<8392, blk, 0, stream>>>(x, xbf, xf8, ei, e16,
                                         W1a, W2a, W1b, W2b, Wlin,
                                         W1aPk, W2aPk, W1bPk, W2bPk, WlinPk,
                                         partial);
    scan1<<<scanBlocks, blk, 0, stream>>>(partial, chunkpref, rowp, part);
    scan3<<<scanBlocks, blk, 0, stream>>>(rowp, part, rowp + N_NODES, scanBlocks);
    csr_fill<<<16 * NCHUNK, blk, 0, stream>>>(src16, dst16, rowp, chunkpref, csr);

    // ---- Layer a: gather + fused MLP (zA -> h1, + fp8 table) ----
    gather_agg_f8_128<<<agg128Blocks, blk, 0, stream>>>(xbf, xf8, rowp, rowp + 1, csr, zA);
    mlp_fused<<<mlpBlocks, blk, 0, stream>>>(zA, IN_CH, W1aPk, b1a, W2aPk, b2a,
                                             h1, h1f8, N_NODES);

    // ---- Layer b: gather + fused MLP (zB -> h2) ----
    gather_agg_f8_256<<<agg256Blocks, blk, 0, stream>>>(h1, h1f8, rowp, rowp + 1, csr, zB);
    mlp_fused<<<mlpBlocks, blk, 0, stream>>>(zB, HID, W1bPk, b1b, W2bPk, b2b,
                                             h2, nullptr, N_NODES);

    // ---- Final linear on [h1 | h2] + fused log_softmax -> d_out ----
    gemm_mfma<<<gemmBlocks, blk, 0, stream>>>(h1, h2, WlinPk, blin, out, N_NODES);
}